// Round 1
// baseline (1274.693 us; speedup 1.0000x reference)
//
#include <hip/hip_runtime.h>

#define NN 100000
#define NE 3200000
#define DIN 128
#define HD 32
#define MID 16
#define OUTD 8
#define LN_EPS 1e-5f

// ---------------- degree / norm ----------------

__global__ void k_init_deg(int* __restrict__ deg) {
    int i = blockIdx.x * blockDim.x + threadIdx.x;
    if (i < NN) deg[i] = 1;  // self-loop
}

__global__ void k_count_deg(const int* __restrict__ dst, int* __restrict__ deg) {
    int e = blockIdx.x * blockDim.x + threadIdx.x;
    if (e < NE) atomicAdd(&deg[dst[e]], 1);
}

__global__ void k_dis(const int* __restrict__ deg, float* __restrict__ dis) {
    int i = blockIdx.x * blockDim.x + threadIdx.x;
    if (i < NN) dis[i] = rsqrtf((float)deg[i]);   // deg >= 1 always (self-loop)
}

// ---------------- GEMMs (fused with self-loop init of agg) ----------------

// h = x @ W0  (N x 128 @ 128 x 32); agg = h * dis^2  (self-loop contribution)
__global__ void k_gemm0(const float* __restrict__ x, const float* __restrict__ W,
                        const float* __restrict__ dis,
                        float* __restrict__ h, float* __restrict__ agg) {
    __shared__ float sW[DIN * HD];
    for (int t = threadIdx.x; t < DIN * HD; t += blockDim.x) sW[t] = W[t];
    __syncthreads();
    int idx = blockIdx.x * blockDim.x + threadIdx.x;
    int n = idx >> 5, j = idx & 31;
    if (n >= NN) return;
    const float* xr = x + (size_t)n * DIN;
    float acc = 0.f;
#pragma unroll 16
    for (int k = 0; k < DIN; ++k) acc += xr[k] * sW[k * HD + j];
    size_t o = (size_t)n * HD + j;
    h[o] = acc;
    float d = dis[n];
    agg[o] = acc * d * d;
}

// h = hin @ W (N x 32 @ 32 x 32); agg = h * dis^2
__global__ void k_gemm_h(const float* __restrict__ hin, const float* __restrict__ W,
                         const float* __restrict__ dis,
                         float* __restrict__ h, float* __restrict__ agg) {
    __shared__ float sW[HD * HD];
    for (int t = threadIdx.x; t < HD * HD; t += blockDim.x) sW[t] = W[t];
    __syncthreads();
    int idx = blockIdx.x * blockDim.x + threadIdx.x;
    int n = idx >> 5, j = idx & 31;
    if (n >= NN) return;
    const float* r = hin + (size_t)n * HD;
    float acc = 0.f;
#pragma unroll
    for (int k = 0; k < HD; ++k) acc += r[k] * sW[k * HD + j];
    size_t o = (size_t)n * HD + j;
    h[o] = acc;
    float d = dis[n];
    agg[o] = acc * d * d;
}

// ---------------- edge scatter ----------------

// one thread per (edge, channel): agg[dst][c] += h[src][c] * dis[src]*dis[dst]
__global__ void k_agg(const int* __restrict__ src, const int* __restrict__ dst,
                      const float* __restrict__ dis, const float* __restrict__ h,
                      float* __restrict__ agg) {
    int idx = blockIdx.x * blockDim.x + threadIdx.x;
    int e = idx >> 5, c = idx & 31;
    if (e >= NE) return;
    int s = src[e], d = dst[e];
    float w = dis[s] * dis[d];
    atomicAdd(&agg[(size_t)d * HD + c], h[(size_t)s * HD + c] * w);
}

// ---------------- bias + relu + layernorm ----------------

__global__ void k_post_ln(const float* __restrict__ agg, const float* __restrict__ bias,
                          const float* __restrict__ g, const float* __restrict__ bln,
                          float* __restrict__ out) {
    int idx = blockIdx.x * blockDim.x + threadIdx.x;
    int n = idx >> 5, j = idx & 31;
    if (n >= NN) return;
    float v = agg[(size_t)n * HD + j] + bias[j];
    v = fmaxf(v, 0.f);
    float s = v, s2 = v * v;
#pragma unroll
    for (int m = 16; m >= 1; m >>= 1) {
        s += __shfl_xor(s, m, 32);
        s2 += __shfl_xor(s2, m, 32);
    }
    float mean = s * (1.f / 32.f);
    float var = s2 * (1.f / 32.f) - mean * mean;
    out[(size_t)n * HD + j] = (v - mean) * rsqrtf(var + LN_EPS) * g[j] + bln[j];
}

// ---------------- final: bias + relu + MLP head + log_softmax ----------------

__global__ void k_final(const float* __restrict__ agg, const float* __restrict__ b2,
                        const float* __restrict__ w1, const float* __restrict__ mb1,
                        const float* __restrict__ w2, const float* __restrict__ mb2,
                        float* __restrict__ out) {
    __shared__ float sw1[HD * MID], sw2[MID * OUTD], sb1[MID], sb2[OUTD], sbias[HD];
    for (int t = threadIdx.x; t < HD * MID; t += blockDim.x) sw1[t] = w1[t];
    for (int t = threadIdx.x; t < MID * OUTD; t += blockDim.x) sw2[t] = w2[t];
    if (threadIdx.x < MID) sb1[threadIdx.x] = mb1[threadIdx.x];
    if (threadIdx.x < OUTD) sb2[threadIdx.x] = mb2[threadIdx.x];
    if (threadIdx.x < HD) sbias[threadIdx.x] = b2[threadIdx.x];
    __syncthreads();
    int n = blockIdx.x * blockDim.x + threadIdx.x;
    if (n >= NN) return;
    float h[HD];
    const float* ar = agg + (size_t)n * HD;
#pragma unroll
    for (int k = 0; k < HD; ++k) h[k] = fmaxf(ar[k] + sbias[k], 0.f);
    float t[MID];
#pragma unroll
    for (int j = 0; j < MID; ++j) {
        float a = sb1[j];
#pragma unroll
        for (int k = 0; k < HD; ++k) a += h[k] * sw1[k * MID + j];
        t[j] = fmaxf(a, 0.f);
    }
    float o[OUTD];
#pragma unroll
    for (int j = 0; j < OUTD; ++j) {
        float a = sb2[j];
#pragma unroll
        for (int k = 0; k < MID; ++k) a += t[k] * sw2[k * OUTD + j];
        o[j] = a;
    }
    float mx = o[0];
#pragma unroll
    for (int j = 1; j < OUTD; ++j) mx = fmaxf(mx, o[j]);
    float se = 0.f;
#pragma unroll
    for (int j = 0; j < OUTD; ++j) se += __expf(o[j] - mx);
    float lse = __logf(se) + mx;
    float* orow = out + (size_t)n * OUTD;
#pragma unroll
    for (int j = 0; j < OUTD; ++j) orow[j] = o[j] - lse;
}

// ---------------- launch ----------------

extern "C" void kernel_launch(void* const* d_in, const int* in_sizes, int n_in,
                              void* d_out, int out_size, void* d_ws, size_t ws_size,
                              hipStream_t stream) {
    const float* x     = (const float*)d_in[0];
    const int*   ei    = (const int*)d_in[1];
    const float* W0    = (const float*)d_in[2];
    const float* b0    = (const float*)d_in[3];
    const float* W1    = (const float*)d_in[4];
    const float* b1    = (const float*)d_in[5];
    const float* W2    = (const float*)d_in[6];
    const float* b2    = (const float*)d_in[7];
    const float* ln0_g = (const float*)d_in[8];
    const float* ln0_b = (const float*)d_in[9];
    const float* ln1_g = (const float*)d_in[10];
    const float* ln1_b = (const float*)d_in[11];
    const float* mp_w1 = (const float*)d_in[12];
    const float* mp_b1 = (const float*)d_in[13];
    const float* mp_w2 = (const float*)d_in[14];
    const float* mp_b2 = (const float*)d_in[15];
    float* out = (float*)d_out;

    const int* src = ei;        // edge_index[0]
    const int* dst = ei + NE;   // edge_index[1]

    float* ws   = (float*)d_ws;
    int*   deg  = (int*)ws;                       // N ints
    float* dis  = ws + NN;                        // N
    float* bufA = ws + 2 * (size_t)NN;            // 32N  (layer input)
    float* bufB = bufA + (size_t)HD * NN;         // 32N  (gemm out h)
    float* bufC = bufB + (size_t)HD * NN;         // 32N  (agg)

    const int BS = 256;
    int gN   = (NN + BS - 1) / BS;
    int gE   = (NE + BS - 1) / BS;
    int gN32 = (NN * HD + BS - 1) / BS;
    int gE32 = (int)(((long long)NE * HD + BS - 1) / BS);

    k_init_deg<<<gN, BS, 0, stream>>>(deg);
    k_count_deg<<<gE, BS, 0, stream>>>(dst, deg);
    k_dis<<<gN, BS, 0, stream>>>(deg, dis);

    // layer 0
    k_gemm0<<<gN32, BS, 0, stream>>>(x, W0, dis, bufB, bufC);
    k_agg<<<gE32, BS, 0, stream>>>(src, dst, dis, bufB, bufC);
    k_post_ln<<<gN32, BS, 0, stream>>>(bufC, b0, ln0_g, ln0_b, bufA);

    // layer 1
    k_gemm_h<<<gN32, BS, 0, stream>>>(bufA, W1, dis, bufB, bufC);
    k_agg<<<gE32, BS, 0, stream>>>(src, dst, dis, bufB, bufC);
    k_post_ln<<<gN32, BS, 0, stream>>>(bufC, b1, ln1_g, ln1_b, bufA);

    // layer 2 (no LN)
    k_gemm_h<<<gN32, BS, 0, stream>>>(bufA, W2, dis, bufB, bufC);
    k_agg<<<gE32, BS, 0, stream>>>(src, dst, dis, bufB, bufC);

    // head
    k_final<<<gN, BS, 0, stream>>>(bufC, b2, mp_w1, mp_b1, mp_w2, mp_b2, out);
}

// Round 2
// 843.765 us; speedup vs baseline: 1.5107x; 1.5107x over previous
//
#include <hip/hip_runtime.h>

#define NN 100000
#define NE 3200000
#define DIN 128
#define HD 32
#define MID 16
#define OUTD 8
#define LN_EPS 1e-5f

// ---------------- degree / norm / CSR build ----------------

__global__ void k_zero_cnt(int* __restrict__ cnt) {
    int i = blockIdx.x * blockDim.x + threadIdx.x;
    if (i < NN) cnt[i] = 0;
}

__global__ void k_hist(const int* __restrict__ dst, int* __restrict__ cnt) {
    int e = blockIdx.x * blockDim.x + threadIdx.x;
    if (e < NE) atomicAdd(&cnt[dst[e]], 1);
}

__global__ void k_dis(const int* __restrict__ cnt, float* __restrict__ dis) {
    int i = blockIdx.x * blockDim.x + threadIdx.x;
    if (i < NN) dis[i] = rsqrtf((float)(cnt[i] + 1));  // +1 self-loop
}

// block-level inclusive scan -> exclusive-within-block + block totals
__global__ void k_scan1(const int* __restrict__ cnt, int* __restrict__ excl,
                        int* __restrict__ bsum) {
    __shared__ int s[256];
    int i = blockIdx.x * 256 + threadIdx.x;
    int v = (i < NN) ? cnt[i] : 0;
    s[threadIdx.x] = v;
    __syncthreads();
#pragma unroll
    for (int off = 1; off < 256; off <<= 1) {
        int t = (threadIdx.x >= off) ? s[threadIdx.x - off] : 0;
        __syncthreads();
        s[threadIdx.x] += t;
        __syncthreads();
    }
    if (i < NN) excl[i] = s[threadIdx.x] - v;
    if (threadIdx.x == 255) bsum[blockIdx.x] = s[255];
}

// single-block exclusive scan of block totals (nblk <= 512)
__global__ void k_scan2(int* __restrict__ bsum, int nblk) {
    __shared__ int s[512];
    int v = (threadIdx.x < nblk) ? bsum[threadIdx.x] : 0;
    s[threadIdx.x] = v;
    __syncthreads();
#pragma unroll
    for (int off = 1; off < 512; off <<= 1) {
        int t = (threadIdx.x >= off) ? s[threadIdx.x - off] : 0;
        __syncthreads();
        s[threadIdx.x] += t;
        __syncthreads();
    }
    if (threadIdx.x < nblk) bsum[threadIdx.x] = s[threadIdx.x] - v;
}

__global__ void k_scan3(const int* __restrict__ excl, const int* __restrict__ bsum,
                        int* __restrict__ row_ptr, int* __restrict__ pos) {
    int i = blockIdx.x * 256 + threadIdx.x;
    if (i < NN) {
        int r = excl[i] + bsum[blockIdx.x];
        row_ptr[i] = r;
        pos[i] = r;
    }
    if (i == 0) row_ptr[NN] = NE;
}

__global__ void k_fill(const int* __restrict__ src, const int* __restrict__ dst,
                       const float* __restrict__ dis, int* __restrict__ pos,
                       int* __restrict__ csr_src, float* __restrict__ csr_w) {
    int e = blockIdx.x * blockDim.x + threadIdx.x;
    if (e >= NE) return;
    int s = src[e], d = dst[e];
    float w = dis[s] * dis[d];
    int slot = atomicAdd(&pos[d], 1);
    csr_src[slot] = s;
    csr_w[slot] = w;
}

// ---------------- GEMMs ----------------

// h = x @ W0  (N x 128 @ 128 x 32)
__global__ void k_gemm0(const float* __restrict__ x, const float* __restrict__ W,
                        float* __restrict__ h) {
    __shared__ float sW[DIN * HD];
    for (int t = threadIdx.x; t < DIN * HD; t += blockDim.x) sW[t] = W[t];
    __syncthreads();
    int idx = blockIdx.x * blockDim.x + threadIdx.x;
    int n = idx >> 5, j = idx & 31;
    if (n >= NN) return;
    const float* xr = x + (size_t)n * DIN;
    float acc = 0.f;
#pragma unroll 16
    for (int k = 0; k < DIN; ++k) acc += xr[k] * sW[k * HD + j];
    h[(size_t)n * HD + j] = acc;
}

// h = hin @ W (N x 32 @ 32 x 32)
__global__ void k_gemm_h(const float* __restrict__ hin, const float* __restrict__ W,
                         float* __restrict__ h) {
    __shared__ float sW[HD * HD];
    for (int t = threadIdx.x; t < HD * HD; t += blockDim.x) sW[t] = W[t];
    __syncthreads();
    int idx = blockIdx.x * blockDim.x + threadIdx.x;
    int n = idx >> 5, j = idx & 31;
    if (n >= NN) return;
    const float* r = hin + (size_t)n * HD;
    float acc = 0.f;
#pragma unroll
    for (int k = 0; k < HD; ++k) acc += r[k] * sW[k * HD + j];
    h[(size_t)n * HD + j] = acc;
}

// ---------------- gather aggregation + fused epilogue ----------------
// 32 lanes = 32 channels of one node. Gathers in-edges from CSR; adds
// self-loop; then bias+ReLU (+optional LayerNorm).

template <int DO_LN>
__global__ void k_gather(const int* __restrict__ row_ptr, const int* __restrict__ csr_src,
                         const float* __restrict__ csr_w, const float* __restrict__ dis,
                         const float* __restrict__ h, const float* __restrict__ bias,
                         const float* __restrict__ g, const float* __restrict__ bln,
                         float* __restrict__ out) {
    int idx = blockIdx.x * blockDim.x + threadIdx.x;
    int n = idx >> 5, c = idx & 31;
    if (n >= NN) return;
    float d = dis[n];
    float acc = h[(size_t)n * HD + c] * d * d;  // self-loop
    int e = row_ptr[n], end = row_ptr[n + 1];
    for (; e + 1 < end; e += 2) {
        int s0 = csr_src[e], s1 = csr_src[e + 1];
        float w0 = csr_w[e], w1 = csr_w[e + 1];
        float v0 = h[(size_t)s0 * HD + c];
        float v1 = h[(size_t)s1 * HD + c];
        acc = fmaf(v0, w0, acc);
        acc = fmaf(v1, w1, acc);
    }
    if (e < end) acc = fmaf(h[(size_t)csr_src[e] * HD + c], csr_w[e], acc);

    float v = fmaxf(acc + bias[c], 0.f);
    if (DO_LN) {
        float s = v, s2 = v * v;
#pragma unroll
        for (int m = 16; m >= 1; m >>= 1) {
            s += __shfl_xor(s, m, 32);
            s2 += __shfl_xor(s2, m, 32);
        }
        float mean = s * (1.f / 32.f);
        float var = s2 * (1.f / 32.f) - mean * mean;
        v = (v - mean) * rsqrtf(var + LN_EPS) * g[c] + bln[c];
    }
    out[(size_t)n * HD + c] = v;
}

// ---------------- final: MLP head + log_softmax (input already bias+relu'd) ----------------

__global__ void k_final(const float* __restrict__ hin,
                        const float* __restrict__ w1, const float* __restrict__ mb1,
                        const float* __restrict__ w2, const float* __restrict__ mb2,
                        float* __restrict__ out) {
    __shared__ float sw1[HD * MID], sw2[MID * OUTD], sb1[MID], sb2[OUTD];
    for (int t = threadIdx.x; t < HD * MID; t += blockDim.x) sw1[t] = w1[t];
    for (int t = threadIdx.x; t < MID * OUTD; t += blockDim.x) sw2[t] = w2[t];
    if (threadIdx.x < MID) sb1[threadIdx.x] = mb1[threadIdx.x];
    if (threadIdx.x < OUTD) sb2[threadIdx.x] = mb2[threadIdx.x];
    __syncthreads();
    int n = blockIdx.x * blockDim.x + threadIdx.x;
    if (n >= NN) return;
    float h[HD];
    const float* ar = hin + (size_t)n * HD;
#pragma unroll
    for (int k = 0; k < HD; ++k) h[k] = ar[k];
    float t[MID];
#pragma unroll
    for (int j = 0; j < MID; ++j) {
        float a = sb1[j];
#pragma unroll
        for (int k = 0; k < HD; ++k) a += h[k] * sw1[k * MID + j];
        t[j] = fmaxf(a, 0.f);
    }
    float o[OUTD];
#pragma unroll
    for (int j = 0; j < OUTD; ++j) {
        float a = sb2[j];
#pragma unroll
        for (int k = 0; k < MID; ++k) a += t[k] * sw2[k * OUTD + j];
        o[j] = a;
    }
    float mx = o[0];
#pragma unroll
    for (int j = 1; j < OUTD; ++j) mx = fmaxf(mx, o[j]);
    float se = 0.f;
#pragma unroll
    for (int j = 0; j < OUTD; ++j) se += __expf(o[j] - mx);
    float lse = __logf(se) + mx;
    float* orow = out + (size_t)n * OUTD;
#pragma unroll
    for (int j = 0; j < OUTD; ++j) orow[j] = o[j] - lse;
}

// ---------------- launch ----------------

extern "C" void kernel_launch(void* const* d_in, const int* in_sizes, int n_in,
                              void* d_out, int out_size, void* d_ws, size_t ws_size,
                              hipStream_t stream) {
    const float* x     = (const float*)d_in[0];
    const int*   ei    = (const int*)d_in[1];
    const float* W0    = (const float*)d_in[2];
    const float* b0    = (const float*)d_in[3];
    const float* W1    = (const float*)d_in[4];
    const float* b1    = (const float*)d_in[5];
    const float* W2    = (const float*)d_in[6];
    const float* b2    = (const float*)d_in[7];
    const float* ln0_g = (const float*)d_in[8];
    const float* ln0_b = (const float*)d_in[9];
    const float* ln1_g = (const float*)d_in[10];
    const float* ln1_b = (const float*)d_in[11];
    const float* mp_w1 = (const float*)d_in[12];
    const float* mp_b1 = (const float*)d_in[13];
    const float* mp_w2 = (const float*)d_in[14];
    const float* mp_b2 = (const float*)d_in[15];
    float* out = (float*)d_out;

    const int* src = ei;        // edge_index[0]
    const int* dst = ei + NE;   // edge_index[1]

    char* w = (char*)d_ws;
    int*   cnt     = (int*)w;            w += (size_t)NN * 4;
    int*   excl    = (int*)w;            w += (size_t)NN * 4;
    int*   bsum    = (int*)w;            w += 512 * 4;
    int*   row_ptr = (int*)w;            w += (size_t)(NN + 1) * 4;
    int*   pos     = (int*)w;            w += (size_t)NN * 4;
    float* dis     = (float*)w;          w += (size_t)NN * 4;
    int*   csr_src = (int*)w;            w += (size_t)NE * 4;
    float* csr_w   = (float*)w;          w += (size_t)NE * 4;
    float* bufA    = (float*)w;          w += (size_t)NN * HD * 4;
    float* bufB    = (float*)w;

    const int BS = 256;
    int gN   = (NN + BS - 1) / BS;          // 391
    int gE   = (NE + BS - 1) / BS;
    int gN32 = (NN * HD + BS - 1) / BS;

    // CSR build
    k_zero_cnt<<<gN, BS, 0, stream>>>(cnt);
    k_hist<<<gE, BS, 0, stream>>>(dst, cnt);
    k_dis<<<gN, BS, 0, stream>>>(cnt, dis);
    k_scan1<<<gN, BS, 0, stream>>>(cnt, excl, bsum);
    k_scan2<<<1, 512, 0, stream>>>(bsum, gN);
    k_scan3<<<gN, BS, 0, stream>>>(excl, bsum, row_ptr, pos);
    k_fill<<<gE, BS, 0, stream>>>(src, dst, dis, pos, csr_src, csr_w);

    // layer 0
    k_gemm0<<<gN32, BS, 0, stream>>>(x, W0, bufB);
    k_gather<1><<<gN32, BS, 0, stream>>>(row_ptr, csr_src, csr_w, dis, bufB, b0,
                                         ln0_g, ln0_b, bufA);
    // layer 1
    k_gemm_h<<<gN32, BS, 0, stream>>>(bufA, W1, bufB);
    k_gather<1><<<gN32, BS, 0, stream>>>(row_ptr, csr_src, csr_w, dis, bufB, b1,
                                         ln1_g, ln1_b, bufA);
    // layer 2 (no LN)
    k_gemm_h<<<gN32, BS, 0, stream>>>(bufA, W2, bufB);
    k_gather<0><<<gN32, BS, 0, stream>>>(row_ptr, csr_src, csr_w, dis, bufB, b2,
                                         nullptr, nullptr, bufA);

    // head
    k_final<<<gN, BS, 0, stream>>>(bufA, mp_w1, mp_b1, mp_w2, mp_b2, out);
}

// Round 3
// 742.363 us; speedup vs baseline: 1.7171x; 1.1366x over previous
//
#include <hip/hip_runtime.h>

#define NN 100000
#define NE 3200000
#define DIN 128
#define HD 32
#define MID 16
#define OUTD 8
#define LN_EPS 1e-5f

// ---------------- bf16 helpers ----------------

__device__ __forceinline__ float bf2f(unsigned short u) {
    union { unsigned int i; float f; } c;
    c.i = ((unsigned int)u) << 16;
    return c.f;
}
__device__ __forceinline__ unsigned short f2bf(float f) {
    union { float f; unsigned int i; } c;
    c.f = f;
    unsigned int r = c.i + 0x7FFFu + ((c.i >> 16) & 1u);  // round-to-nearest-even
    return (unsigned short)(r >> 16);
}

// ---------------- degree / norm / CSR build ----------------

__global__ void k_zero_cnt(int* __restrict__ cnt) {
    int i = blockIdx.x * blockDim.x + threadIdx.x;
    if (i < NN) cnt[i] = 0;
}

__global__ void k_hist(const int* __restrict__ dst, int* __restrict__ cnt) {
    int e = blockIdx.x * blockDim.x + threadIdx.x;
    if (e < NE) atomicAdd(&cnt[dst[e]], 1);
}

__global__ void k_dis(const int* __restrict__ cnt, float* __restrict__ dis) {
    int i = blockIdx.x * blockDim.x + threadIdx.x;
    if (i < NN) dis[i] = rsqrtf((float)(cnt[i] + 1));  // +1 self-loop
}

// block-level inclusive scan -> exclusive-within-block + block totals
__global__ void k_scan1(const int* __restrict__ cnt, int* __restrict__ excl,
                        int* __restrict__ bsum) {
    __shared__ int s[256];
    int i = blockIdx.x * 256 + threadIdx.x;
    int v = (i < NN) ? cnt[i] : 0;
    s[threadIdx.x] = v;
    __syncthreads();
#pragma unroll
    for (int off = 1; off < 256; off <<= 1) {
        int t = (threadIdx.x >= off) ? s[threadIdx.x - off] : 0;
        __syncthreads();
        s[threadIdx.x] += t;
        __syncthreads();
    }
    if (i < NN) excl[i] = s[threadIdx.x] - v;
    if (threadIdx.x == 255) bsum[blockIdx.x] = s[255];
}

// single-block exclusive scan of block totals (nblk <= 512)
__global__ void k_scan2(int* __restrict__ bsum, int nblk) {
    __shared__ int s[512];
    int v = (threadIdx.x < nblk) ? bsum[threadIdx.x] : 0;
    s[threadIdx.x] = v;
    __syncthreads();
#pragma unroll
    for (int off = 1; off < 512; off <<= 1) {
        int t = (threadIdx.x >= off) ? s[threadIdx.x - off] : 0;
        __syncthreads();
        s[threadIdx.x] += t;
        __syncthreads();
    }
    if (threadIdx.x < nblk) bsum[threadIdx.x] = s[threadIdx.x] - v;
}

__global__ void k_scan3(const int* __restrict__ excl, const int* __restrict__ bsum,
                        int* __restrict__ row_ptr, int* __restrict__ pos) {
    int i = blockIdx.x * 256 + threadIdx.x;
    if (i < NN) {
        int r = excl[i] + bsum[blockIdx.x];
        row_ptr[i] = r;
        pos[i] = r;
    }
    if (i == 0) row_ptr[NN] = NE;
}

// one random 4B store per edge (src only; weight recomputed in gather)
__global__ void k_fill(const int* __restrict__ src, const int* __restrict__ dst,
                       int* __restrict__ pos, int* __restrict__ csr_src) {
    int e = blockIdx.x * blockDim.x + threadIdx.x;
    if (e >= NE) return;
    int d = dst[e];
    int slot = atomicAdd(&pos[d], 1);
    csr_src[slot] = src[e];
}

// ---------------- GEMMs (write bf16 h) ----------------

// h = x @ W0  (N x 128 @ 128 x 32)
__global__ void k_gemm0(const float* __restrict__ x, const float* __restrict__ W,
                        unsigned short* __restrict__ h) {
    __shared__ float sW[DIN * HD];
    for (int t = threadIdx.x; t < DIN * HD; t += blockDim.x) sW[t] = W[t];
    __syncthreads();
    int idx = blockIdx.x * blockDim.x + threadIdx.x;
    int n = idx >> 5, j = idx & 31;
    if (n >= NN) return;
    const float* xr = x + (size_t)n * DIN;
    float acc = 0.f;
#pragma unroll 16
    for (int k = 0; k < DIN; ++k) acc += xr[k] * sW[k * HD + j];
    h[(size_t)n * HD + j] = f2bf(acc);
}

// h = hin @ W (N x 32 @ 32 x 32)
__global__ void k_gemm_h(const float* __restrict__ hin, const float* __restrict__ W,
                         unsigned short* __restrict__ h) {
    __shared__ float sW[HD * HD];
    for (int t = threadIdx.x; t < HD * HD; t += blockDim.x) sW[t] = W[t];
    __syncthreads();
    int idx = blockIdx.x * blockDim.x + threadIdx.x;
    int n = idx >> 5, j = idx & 31;
    if (n >= NN) return;
    const float* r = hin + (size_t)n * HD;
    float acc = 0.f;
#pragma unroll
    for (int k = 0; k < HD; ++k) acc += r[k] * sW[k * HD + j];
    h[(size_t)n * HD + j] = f2bf(acc);
}

// ---------------- gather aggregation + fused epilogue ----------------
// 32 lanes = 32 channels of one node. Gathers in-edges from CSR; adds
// self-loop; then bias+ReLU (+optional LayerNorm).

template <int DO_LN>
__global__ void k_gather(const int* __restrict__ row_ptr, const int* __restrict__ csr_src,
                         const float* __restrict__ dis,
                         const unsigned short* __restrict__ h,
                         const float* __restrict__ bias,
                         const float* __restrict__ g, const float* __restrict__ bln,
                         float* __restrict__ out) {
    int idx = blockIdx.x * blockDim.x + threadIdx.x;
    int n = idx >> 5, c = idx & 31;
    if (n >= NN) return;
    float d = dis[n];
    float acc = bf2f(h[(size_t)n * HD + c]) * d * d;  // self-loop
    int e = row_ptr[n], end = row_ptr[n + 1];
    for (; e + 3 < end; e += 4) {
        int s0 = csr_src[e], s1 = csr_src[e + 1];
        int s2 = csr_src[e + 2], s3 = csr_src[e + 3];
        float w0 = dis[s0] * d, w1 = dis[s1] * d;
        float w2 = dis[s2] * d, w3 = dis[s3] * d;
        float v0 = bf2f(h[(size_t)s0 * HD + c]);
        float v1 = bf2f(h[(size_t)s1 * HD + c]);
        float v2 = bf2f(h[(size_t)s2 * HD + c]);
        float v3 = bf2f(h[(size_t)s3 * HD + c]);
        acc = fmaf(v0, w0, acc);
        acc = fmaf(v1, w1, acc);
        acc = fmaf(v2, w2, acc);
        acc = fmaf(v3, w3, acc);
    }
    for (; e < end; ++e) {
        int s = csr_src[e];
        acc = fmaf(bf2f(h[(size_t)s * HD + c]), dis[s] * d, acc);
    }

    float v = fmaxf(acc + bias[c], 0.f);
    if (DO_LN) {
        float s = v, s2 = v * v;
#pragma unroll
        for (int m = 16; m >= 1; m >>= 1) {
            s += __shfl_xor(s, m, 32);
            s2 += __shfl_xor(s2, m, 32);
        }
        float mean = s * (1.f / 32.f);
        float var = s2 * (1.f / 32.f) - mean * mean;
        v = (v - mean) * rsqrtf(var + LN_EPS) * g[c] + bln[c];
    }
    out[(size_t)n * HD + c] = v;
}

// ---------------- final: MLP head + log_softmax (input already bias+relu'd) ----------------

__global__ void k_final(const float* __restrict__ hin,
                        const float* __restrict__ w1, const float* __restrict__ mb1,
                        const float* __restrict__ w2, const float* __restrict__ mb2,
                        float* __restrict__ out) {
    __shared__ float sw1[HD * MID], sw2[MID * OUTD], sb1[MID], sb2[OUTD];
    for (int t = threadIdx.x; t < HD * MID; t += blockDim.x) sw1[t] = w1[t];
    for (int t = threadIdx.x; t < MID * OUTD; t += blockDim.x) sw2[t] = w2[t];
    if (threadIdx.x < MID) sb1[threadIdx.x] = mb1[threadIdx.x];
    if (threadIdx.x < OUTD) sb2[threadIdx.x] = mb2[threadIdx.x];
    __syncthreads();
    int n = blockIdx.x * blockDim.x + threadIdx.x;
    if (n >= NN) return;
    float h[HD];
    const float* ar = hin + (size_t)n * HD;
#pragma unroll
    for (int k = 0; k < HD; ++k) h[k] = ar[k];
    float t[MID];
#pragma unroll
    for (int j = 0; j < MID; ++j) {
        float a = sb1[j];
#pragma unroll
        for (int k = 0; k < HD; ++k) a += h[k] * sw1[k * MID + j];
        t[j] = fmaxf(a, 0.f);
    }
    float o[OUTD];
#pragma unroll
    for (int j = 0; j < OUTD; ++j) {
        float a = sb2[j];
#pragma unroll
        for (int k = 0; k < MID; ++k) a += t[k] * sw2[k * OUTD + j];
        o[j] = a;
    }
    float mx = o[0];
#pragma unroll
    for (int j = 1; j < OUTD; ++j) mx = fmaxf(mx, o[j]);
    float se = 0.f;
#pragma unroll
    for (int j = 0; j < OUTD; ++j) se += __expf(o[j] - mx);
    float lse = __logf(se) + mx;
    float* orow = out + (size_t)n * OUTD;
#pragma unroll
    for (int j = 0; j < OUTD; ++j) orow[j] = o[j] - lse;
}

// ---------------- launch ----------------

extern "C" void kernel_launch(void* const* d_in, const int* in_sizes, int n_in,
                              void* d_out, int out_size, void* d_ws, size_t ws_size,
                              hipStream_t stream) {
    const float* x     = (const float*)d_in[0];
    const int*   ei    = (const int*)d_in[1];
    const float* W0    = (const float*)d_in[2];
    const float* b0    = (const float*)d_in[3];
    const float* W1    = (const float*)d_in[4];
    const float* b1    = (const float*)d_in[5];
    const float* W2    = (const float*)d_in[6];
    const float* b2    = (const float*)d_in[7];
    const float* ln0_g = (const float*)d_in[8];
    const float* ln0_b = (const float*)d_in[9];
    const float* ln1_g = (const float*)d_in[10];
    const float* ln1_b = (const float*)d_in[11];
    const float* mp_w1 = (const float*)d_in[12];
    const float* mp_b1 = (const float*)d_in[13];
    const float* mp_w2 = (const float*)d_in[14];
    const float* mp_b2 = (const float*)d_in[15];
    float* out = (float*)d_out;

    const int* src = ei;        // edge_index[0]
    const int* dst = ei + NE;   // edge_index[1]

    char* w = (char*)d_ws;
    int*   cnt     = (int*)w;              w += (size_t)NN * 4;
    int*   excl    = (int*)w;              w += (size_t)NN * 4;
    int*   bsum    = (int*)w;              w += 512 * 4;
    int*   row_ptr = (int*)w;              w += (size_t)(NN + 1) * 4;
    int*   pos     = (int*)w;              w += (size_t)NN * 4;
    float* dis     = (float*)w;            w += (size_t)NN * 4;
    int*   csr_src = (int*)w;              w += (size_t)NE * 4;
    unsigned short* bufB = (unsigned short*)w;  w += (size_t)NN * HD * 2;  // bf16 h
    float* bufA    = (float*)w;            w += (size_t)NN * HD * 4;       // f32 activations

    const int BS = 256;
    int gN   = (NN + BS - 1) / BS;          // 391
    int gE   = (NE + BS - 1) / BS;
    int gN32 = (NN * HD + BS - 1) / BS;

    // CSR build
    k_zero_cnt<<<gN, BS, 0, stream>>>(cnt);
    k_hist<<<gE, BS, 0, stream>>>(dst, cnt);
    k_dis<<<gN, BS, 0, stream>>>(cnt, dis);
    k_scan1<<<gN, BS, 0, stream>>>(cnt, excl, bsum);
    k_scan2<<<1, 512, 0, stream>>>(bsum, gN);
    k_scan3<<<gN, BS, 0, stream>>>(excl, bsum, row_ptr, pos);
    k_fill<<<gE, BS, 0, stream>>>(src, dst, pos, csr_src);

    // layer 0
    k_gemm0<<<gN32, BS, 0, stream>>>(x, W0, bufB);
    k_gather<1><<<gN32, BS, 0, stream>>>(row_ptr, csr_src, dis, bufB, b0,
                                         ln0_g, ln0_b, bufA);
    // layer 1
    k_gemm_h<<<gN32, BS, 0, stream>>>(bufA, W1, bufB);
    k_gather<1><<<gN32, BS, 0, stream>>>(row_ptr, csr_src, dis, bufB, b1,
                                         ln1_g, ln1_b, bufA);
    // layer 2 (no LN)
    k_gemm_h<<<gN32, BS, 0, stream>>>(bufA, W2, bufB);
    k_gather<0><<<gN32, BS, 0, stream>>>(row_ptr, csr_src, dis, bufB, b2,
                                         nullptr, nullptr, bufA);

    // head
    k_final<<<gN, BS, 0, stream>>>(bufA, mp_w1, mp_b1, mp_w2, mp_b2, out);
}

// Round 4
// 400.847 us; speedup vs baseline: 3.1800x; 1.8520x over previous
//
#include <hip/hip_runtime.h>

#define NN 100000
#define NE 3200000
#define DIN 128
#define HD 32
#define MID 16
#define OUTD 8
#define LN_EPS 1e-5f

#define BINSHIFT 8                 // 256 nodes per bin
#define NB 391                     // ceil(NN / 256)
#define CAP 10240                  // bin capacity (mean 8192, +22 sigma)
#define EPB 8192                   // edges per pass-A block

// ---------------- bf16 helpers ----------------

__device__ __forceinline__ float bf2f(unsigned short u) {
    union { unsigned int i; float f; } c;
    c.i = ((unsigned int)u) << 16;
    return c.f;
}
__device__ __forceinline__ unsigned short f2bf(float f) {
    union { float f; unsigned int i; } c;
    c.f = f;
    unsigned int r = c.i + 0x7FFFu + ((c.i >> 16) & 1u);  // round-to-nearest-even
    return (unsigned short)(r >> 16);
}

// ---------------- binned CSR build ----------------

__global__ void k_zero_bins(int* __restrict__ g_bincur) {
    int i = blockIdx.x * blockDim.x + threadIdx.x;
    if (i < NB) g_bincur[i] = 0;
}

// Pass A: LDS-binned staging. One block = 8192 edges; per-block per-bin
// contiguous runs reserved with one global atomic each.
__global__ void k_binA(const int* __restrict__ src, const int* __restrict__ dst,
                       int* __restrict__ g_bincur, unsigned int* __restrict__ staged) {
    __shared__ int cnt[NB];
    __shared__ int base[NB];
    for (int t = threadIdx.x; t < NB; t += 256) cnt[t] = 0;
    __syncthreads();
    int e0 = blockIdx.x * EPB;
#pragma unroll
    for (int i = 0; i < 32; ++i) {
        int e = e0 + i * 256 + threadIdx.x;
        if (e < NE) atomicAdd(&cnt[dst[e] >> BINSHIFT], 1);
    }
    __syncthreads();
    for (int t = threadIdx.x; t < NB; t += 256) {
        int c = cnt[t];
        base[t] = c ? atomicAdd(&g_bincur[t], c) : 0;
        cnt[t] = 0;  // reuse as intra-block cursor
    }
    __syncthreads();
#pragma unroll
    for (int i = 0; i < 32; ++i) {
        int e = e0 + i * 256 + threadIdx.x;
        if (e < NE) {
            int d = dst[e];
            int b = d >> BINSHIFT;
            int k = base[b] + atomicAdd(&cnt[b], 1);
            if (k < CAP)
                staged[(size_t)b * CAP + k] =
                    ((unsigned int)(d & 255) << 24) | (unsigned int)src[e];
        }
    }
}

// exclusive scan of bin totals (NB <= 512); also writes row_ptr[NN]
__global__ void k_binscan(const int* __restrict__ g_bincur, int* __restrict__ g_binexcl,
                          int* __restrict__ row_ptr) {
    __shared__ int s[512];
    int v = (threadIdx.x < NB) ? min(g_bincur[threadIdx.x], CAP) : 0;
    s[threadIdx.x] = v;
    __syncthreads();
#pragma unroll
    for (int off = 1; off < 512; off <<= 1) {
        int t = (threadIdx.x >= off) ? s[threadIdx.x - off] : 0;
        __syncthreads();
        s[threadIdx.x] += t;
        __syncthreads();
    }
    if (threadIdx.x < NB) g_binexcl[threadIdx.x] = s[threadIdx.x] - v;
    if (threadIdx.x == NB - 1) row_ptr[NN] = s[threadIdx.x];
}

// Pass C: one block per bin. Local count+scan -> row_ptr & dis (coalesced),
// then scatter csr_src within the block's exclusive contiguous region.
__global__ void k_binC(const int* __restrict__ g_bincur, const int* __restrict__ g_binexcl,
                       const unsigned int* __restrict__ staged,
                       int* __restrict__ row_ptr, float* __restrict__ dis,
                       int* __restrict__ csr_src) {
    __shared__ int cnt[256];
    __shared__ int scn[256];
    int b = blockIdx.x;
    int tot = min(g_bincur[b], CAP);
    cnt[threadIdx.x] = 0;
    __syncthreads();
    const unsigned int* st = staged + (size_t)b * CAP;
    for (int i = threadIdx.x; i < tot; i += 256)
        atomicAdd(&cnt[st[i] >> 24], 1);
    __syncthreads();
    int v = cnt[threadIdx.x];
    scn[threadIdx.x] = v;
    __syncthreads();
#pragma unroll
    for (int off = 1; off < 256; off <<= 1) {
        int t = (threadIdx.x >= off) ? scn[threadIdx.x - off] : 0;
        __syncthreads();
        scn[threadIdx.x] += t;
        __syncthreads();
    }
    int excl = scn[threadIdx.x] - v;
    int gbase = g_binexcl[b];
    int node = (b << BINSHIFT) + threadIdx.x;
    if (node < NN) {
        row_ptr[node] = gbase + excl;
        dis[node] = rsqrtf((float)(v + 1));  // +1 self-loop
    }
    cnt[threadIdx.x] = excl;  // reuse as scatter cursor
    __syncthreads();
    for (int i = threadIdx.x; i < tot; i += 256) {
        unsigned int p = st[i];
        int rank = atomicAdd(&cnt[p >> 24], 1);
        csr_src[gbase + rank] = (int)(p & 0xFFFFFFu);
    }
}

// ---------------- GEMMs (write bf16 h) ----------------

__global__ void k_gemm0(const float* __restrict__ x, const float* __restrict__ W,
                        unsigned short* __restrict__ h) {
    __shared__ float sW[DIN * HD];
    for (int t = threadIdx.x; t < DIN * HD; t += blockDim.x) sW[t] = W[t];
    __syncthreads();
    int idx = blockIdx.x * blockDim.x + threadIdx.x;
    int n = idx >> 5, j = idx & 31;
    if (n >= NN) return;
    const float* xr = x + (size_t)n * DIN;
    float acc = 0.f;
#pragma unroll 16
    for (int k = 0; k < DIN; ++k) acc += xr[k] * sW[k * HD + j];
    h[(size_t)n * HD + j] = f2bf(acc);
}

__global__ void k_gemm_h(const float* __restrict__ hin, const float* __restrict__ W,
                         unsigned short* __restrict__ h) {
    __shared__ float sW[HD * HD];
    for (int t = threadIdx.x; t < HD * HD; t += blockDim.x) sW[t] = W[t];
    __syncthreads();
    int idx = blockIdx.x * blockDim.x + threadIdx.x;
    int n = idx >> 5, j = idx & 31;
    if (n >= NN) return;
    const float* r = hin + (size_t)n * HD;
    float acc = 0.f;
#pragma unroll
    for (int k = 0; k < HD; ++k) acc += r[k] * sW[k * HD + j];
    h[(size_t)n * HD + j] = f2bf(acc);
}

// ---------------- gather aggregation + fused epilogue ----------------

template <int DO_LN>
__global__ void k_gather(const int* __restrict__ row_ptr, const int* __restrict__ csr_src,
                         const float* __restrict__ dis,
                         const unsigned short* __restrict__ h,
                         const float* __restrict__ bias,
                         const float* __restrict__ g, const float* __restrict__ bln,
                         float* __restrict__ out) {
    int idx = blockIdx.x * blockDim.x + threadIdx.x;
    int n = idx >> 5, c = idx & 31;
    if (n >= NN) return;
    float d = dis[n];
    float acc = bf2f(h[(size_t)n * HD + c]) * d * d;  // self-loop
    int e = row_ptr[n], end = row_ptr[n + 1];
    for (; e + 3 < end; e += 4) {
        int s0 = csr_src[e], s1 = csr_src[e + 1];
        int s2 = csr_src[e + 2], s3 = csr_src[e + 3];
        float w0 = dis[s0] * d, w1 = dis[s1] * d;
        float w2 = dis[s2] * d, w3 = dis[s3] * d;
        float v0 = bf2f(h[(size_t)s0 * HD + c]);
        float v1 = bf2f(h[(size_t)s1 * HD + c]);
        float v2 = bf2f(h[(size_t)s2 * HD + c]);
        float v3 = bf2f(h[(size_t)s3 * HD + c]);
        acc = fmaf(v0, w0, acc);
        acc = fmaf(v1, w1, acc);
        acc = fmaf(v2, w2, acc);
        acc = fmaf(v3, w3, acc);
    }
    for (; e < end; ++e) {
        int s = csr_src[e];
        acc = fmaf(bf2f(h[(size_t)s * HD + c]), dis[s] * d, acc);
    }

    float v = fmaxf(acc + bias[c], 0.f);
    if (DO_LN) {
        float s = v, s2 = v * v;
#pragma unroll
        for (int m = 16; m >= 1; m >>= 1) {
            s += __shfl_xor(s, m, 32);
            s2 += __shfl_xor(s2, m, 32);
        }
        float mean = s * (1.f / 32.f);
        float var = s2 * (1.f / 32.f) - mean * mean;
        v = (v - mean) * rsqrtf(var + LN_EPS) * g[c] + bln[c];
    }
    out[(size_t)n * HD + c] = v;
}

// ---------------- final: MLP head + log_softmax ----------------

__global__ void k_final(const float* __restrict__ hin,
                        const float* __restrict__ w1, const float* __restrict__ mb1,
                        const float* __restrict__ w2, const float* __restrict__ mb2,
                        float* __restrict__ out) {
    __shared__ float sw1[HD * MID], sw2[MID * OUTD], sb1[MID], sb2[OUTD];
    for (int t = threadIdx.x; t < HD * MID; t += blockDim.x) sw1[t] = w1[t];
    for (int t = threadIdx.x; t < MID * OUTD; t += blockDim.x) sw2[t] = w2[t];
    if (threadIdx.x < MID) sb1[threadIdx.x] = mb1[threadIdx.x];
    if (threadIdx.x < OUTD) sb2[threadIdx.x] = mb2[threadIdx.x];
    __syncthreads();
    int n = blockIdx.x * blockDim.x + threadIdx.x;
    if (n >= NN) return;
    float h[HD];
    const float* ar = hin + (size_t)n * HD;
#pragma unroll
    for (int k = 0; k < HD; ++k) h[k] = ar[k];
    float t[MID];
#pragma unroll
    for (int j = 0; j < MID; ++j) {
        float a = sb1[j];
#pragma unroll
        for (int k = 0; k < HD; ++k) a += h[k] * sw1[k * MID + j];
        t[j] = fmaxf(a, 0.f);
    }
    float o[OUTD];
#pragma unroll
    for (int j = 0; j < OUTD; ++j) {
        float a = sb2[j];
#pragma unroll
        for (int k = 0; k < MID; ++k) a += t[k] * sw2[k * OUTD + j];
        o[j] = a;
    }
    float mx = o[0];
#pragma unroll
    for (int j = 1; j < OUTD; ++j) mx = fmaxf(mx, o[j]);
    float se = 0.f;
#pragma unroll
    for (int j = 0; j < OUTD; ++j) se += __expf(o[j] - mx);
    float lse = __logf(se) + mx;
    float* orow = out + (size_t)n * OUTD;
#pragma unroll
    for (int j = 0; j < OUTD; ++j) orow[j] = o[j] - lse;
}

// ---------------- launch ----------------

extern "C" void kernel_launch(void* const* d_in, const int* in_sizes, int n_in,
                              void* d_out, int out_size, void* d_ws, size_t ws_size,
                              hipStream_t stream) {
    const float* x     = (const float*)d_in[0];
    const int*   ei    = (const int*)d_in[1];
    const float* W0    = (const float*)d_in[2];
    const float* b0    = (const float*)d_in[3];
    const float* W1    = (const float*)d_in[4];
    const float* b1    = (const float*)d_in[5];
    const float* W2    = (const float*)d_in[6];
    const float* b2    = (const float*)d_in[7];
    const float* ln0_g = (const float*)d_in[8];
    const float* ln0_b = (const float*)d_in[9];
    const float* ln1_g = (const float*)d_in[10];
    const float* ln1_b = (const float*)d_in[11];
    const float* mp_w1 = (const float*)d_in[12];
    const float* mp_b1 = (const float*)d_in[13];
    const float* mp_w2 = (const float*)d_in[14];
    const float* mp_b2 = (const float*)d_in[15];
    float* out = (float*)d_out;

    const int* src = ei;        // edge_index[0]
    const int* dst = ei + NE;   // edge_index[1]

    // workspace layout (staging aliased over bufB/bufA — disjoint lifetimes)
    char* w = (char*)d_ws;
    auto align256 = [](size_t v) { return (v + 255) & ~(size_t)255; };
    int* g_bincur  = (int*)w;   w += align256((size_t)NB * 4);
    int* g_binexcl = (int*)w;   w += align256((size_t)NB * 4);
    int* row_ptr   = (int*)w;   w += align256((size_t)(NN + 1) * 4);
    float* dis     = (float*)w; w += align256((size_t)NN * 4);
    char* uni = w;              // union region
    unsigned int* staged = (unsigned int*)uni;                    // NB*CAP*4 = 16.0 MB
    unsigned short* bufB = (unsigned short*)uni;                  // bf16 h, 6.4 MB
    float* bufA = (float*)(uni + align256((size_t)NN * HD * 2));  // f32 acts, 12.8 MB
    size_t uni_sz = align256((size_t)NB * CAP * 4);
    size_t uni_sz2 = align256((size_t)NN * HD * 2) + align256((size_t)NN * HD * 4);
    w = uni + (uni_sz > uni_sz2 ? uni_sz : uni_sz2);
    int* csr_src = (int*)w;

    const int BS = 256;
    int gN   = (NN + BS - 1) / BS;
    int gA   = (NE + EPB - 1) / EPB;        // 391
    int gN32 = (NN * HD + BS - 1) / BS;

    // CSR build (binned counting sort)
    k_zero_bins<<<1, 512, 0, stream>>>(g_bincur);
    k_binA<<<gA, BS, 0, stream>>>(src, dst, g_bincur, staged);
    k_binscan<<<1, 512, 0, stream>>>(g_bincur, g_binexcl, row_ptr);
    k_binC<<<NB, BS, 0, stream>>>(g_bincur, g_binexcl, staged, row_ptr, dis, csr_src);

    // layer 0
    k_gemm0<<<gN32, BS, 0, stream>>>(x, W0, bufB);
    k_gather<1><<<gN32, BS, 0, stream>>>(row_ptr, csr_src, dis, bufB, b0,
                                         ln0_g, ln0_b, bufA);
    // layer 1
    k_gemm_h<<<gN32, BS, 0, stream>>>(bufA, W1, bufB);
    k_gather<1><<<gN32, BS, 0, stream>>>(row_ptr, csr_src, dis, bufB, b1,
                                         ln1_g, ln1_b, bufA);
    // layer 2 (no LN)
    k_gemm_h<<<gN32, BS, 0, stream>>>(bufA, W2, bufB);
    k_gather<0><<<gN32, BS, 0, stream>>>(row_ptr, csr_src, dis, bufB, b2,
                                         nullptr, nullptr, bufA);

    // head
    k_final<<<gN, BS, 0, stream>>>(bufA, mp_w1, mp_b1, mp_w2, mp_b2, out);
}

// Round 5
// 327.685 us; speedup vs baseline: 3.8900x; 1.2233x over previous
//
#include <hip/hip_runtime.h>

#define NN 100000
#define NE 3200000
#define DIN 128
#define HD 32
#define MID 16
#define OUTD 8
#define LN_EPS 1e-5f

#define BINSHIFT 8                 // 256 nodes per bin
#define NB 391                     // ceil(NN / 256)
#define CAP 10240                  // bin capacity (mean 8192)
#define EPB 8192                   // edges per pass-A block

// ---------------- bf16 helpers ----------------

__device__ __forceinline__ float bf2f(unsigned short u) {
    union { unsigned int i; float f; } c;
    c.i = ((unsigned int)u) << 16;
    return c.f;
}
__device__ __forceinline__ unsigned short f2bf(float f) {
    union { float f; unsigned int i; } c;
    c.f = f;
    unsigned int r = c.i + 0x7FFFu + ((c.i >> 16) & 1u);  // RNE
    return (unsigned short)(r >> 16);
}
__device__ __forceinline__ unsigned int pack2(float a, float b) {
    return (unsigned int)f2bf(a) | ((unsigned int)f2bf(b) << 16);
}

// ---------------- binned CSR build ----------------

__global__ void k_zero_bins(int* __restrict__ g_bincur) {
    int i = blockIdx.x * blockDim.x + threadIdx.x;
    if (i < NB) g_bincur[i] = 0;
}

__global__ void k_binA(const int* __restrict__ src, const int* __restrict__ dst,
                       int* __restrict__ g_bincur, unsigned int* __restrict__ staged) {
    __shared__ int cnt[NB];
    __shared__ int base[NB];
    for (int t = threadIdx.x; t < NB; t += 256) cnt[t] = 0;
    __syncthreads();
    int e0 = blockIdx.x * EPB;
#pragma unroll
    for (int i = 0; i < 32; ++i) {
        int e = e0 + i * 256 + threadIdx.x;
        if (e < NE) atomicAdd(&cnt[dst[e] >> BINSHIFT], 1);
    }
    __syncthreads();
    for (int t = threadIdx.x; t < NB; t += 256) {
        int c = cnt[t];
        base[t] = c ? atomicAdd(&g_bincur[t], c) : 0;
        cnt[t] = 0;  // reuse as intra-block cursor
    }
    __syncthreads();
#pragma unroll
    for (int i = 0; i < 32; ++i) {
        int e = e0 + i * 256 + threadIdx.x;
        if (e < NE) {
            int d = dst[e];
            int b = d >> BINSHIFT;
            int k = base[b] + atomicAdd(&cnt[b], 1);
            if (k < CAP)
                staged[(size_t)b * CAP + k] =
                    ((unsigned int)(d & 255) << 24) | (unsigned int)src[e];
        }
    }
}

__global__ void k_binscan(const int* __restrict__ g_bincur, int* __restrict__ g_binexcl,
                          int* __restrict__ row_ptr) {
    __shared__ int s[512];
    int v = (threadIdx.x < NB) ? min(g_bincur[threadIdx.x], CAP) : 0;
    s[threadIdx.x] = v;
    __syncthreads();
#pragma unroll
    for (int off = 1; off < 512; off <<= 1) {
        int t = (threadIdx.x >= off) ? s[threadIdx.x - off] : 0;
        __syncthreads();
        s[threadIdx.x] += t;
        __syncthreads();
    }
    if (threadIdx.x < NB) g_binexcl[threadIdx.x] = s[threadIdx.x] - v;
    if (threadIdx.x == NB - 1) row_ptr[NN] = s[threadIdx.x];
}

__global__ void k_binC(const int* __restrict__ g_bincur, const int* __restrict__ g_binexcl,
                       const unsigned int* __restrict__ staged,
                       int* __restrict__ row_ptr, float* __restrict__ dis,
                       int* __restrict__ csr_src) {
    __shared__ int cnt[256];
    __shared__ int scn[256];
    int b = blockIdx.x;
    int tot = min(g_bincur[b], CAP);
    cnt[threadIdx.x] = 0;
    __syncthreads();
    const unsigned int* st = staged + (size_t)b * CAP;
    for (int i = threadIdx.x; i < tot; i += 256)
        atomicAdd(&cnt[st[i] >> 24], 1);
    __syncthreads();
    int v = cnt[threadIdx.x];
    scn[threadIdx.x] = v;
    __syncthreads();
#pragma unroll
    for (int off = 1; off < 256; off <<= 1) {
        int t = (threadIdx.x >= off) ? scn[threadIdx.x - off] : 0;
        __syncthreads();
        scn[threadIdx.x] += t;
        __syncthreads();
    }
    int excl = scn[threadIdx.x] - v;
    int gbase = g_binexcl[b];
    int node = (b << BINSHIFT) + threadIdx.x;
    if (node < NN) {
        row_ptr[node] = gbase + excl;
        dis[node] = rsqrtf((float)(v + 1));  // +1 self-loop
    }
    cnt[threadIdx.x] = excl;  // reuse as scatter cursor
    __syncthreads();
    for (int i = threadIdx.x; i < tot; i += 256) {
        unsigned int p = st[i];
        int rank = atomicAdd(&cnt[p >> 24], 1);
        csr_src[gbase + rank] = (int)(p & 0xFFFFFFu);
    }
}

// ---------------- GEMM: thread = node, W via uniform (SGPR) loads ----------------
// hs[n][j] = (x[n] @ W)[j] * dis[n]  packed bf16

template <int K>
__global__ void k_gemm(const float* __restrict__ x, const float* __restrict__ W,
                       const float* __restrict__ dis, unsigned short* __restrict__ hs) {
    int n = blockIdx.x * blockDim.x + threadIdx.x;
    if (n >= NN) return;
    float d = dis[n];
    const float* xr = x + (size_t)n * K;
    float acc[HD];
#pragma unroll
    for (int j = 0; j < HD; ++j) acc[j] = 0.f;
    for (int k0 = 0; k0 < K; k0 += 4) {
        float4 xv = *reinterpret_cast<const float4*>(xr + k0);
#pragma unroll
        for (int kk = 0; kk < 4; ++kk) {
            float xk = kk == 0 ? xv.x : kk == 1 ? xv.y : kk == 2 ? xv.z : xv.w;
#pragma unroll
            for (int j = 0; j < HD; ++j)
                acc[j] = fmaf(xk, W[(k0 + kk) * HD + j], acc[j]);  // W uniform -> s_load
        }
    }
    uint4* hv = reinterpret_cast<uint4*>(hs + (size_t)n * HD);
#pragma unroll
    for (int q = 0; q < 4; ++q) {
        uint4 p;
        p.x = pack2(acc[q * 8 + 0] * d, acc[q * 8 + 1] * d);
        p.y = pack2(acc[q * 8 + 2] * d, acc[q * 8 + 3] * d);
        p.z = pack2(acc[q * 8 + 4] * d, acc[q * 8 + 5] * d);
        p.w = pack2(acc[q * 8 + 6] * d, acc[q * 8 + 7] * d);
        hv[q] = p;
    }
}

// ---------------- gather: out = dis[n]*(hs[n] + sum hs[src]) + epilogue ----------------

template <int DO_LN>
__global__ void k_gather(const int* __restrict__ row_ptr, const int* __restrict__ csr_src,
                         const float* __restrict__ dis,
                         const unsigned short* __restrict__ h,
                         const float* __restrict__ bias,
                         const float* __restrict__ g, const float* __restrict__ bln,
                         float* __restrict__ out) {
    int idx = blockIdx.x * blockDim.x + threadIdx.x;
    int n = idx >> 5, c = idx & 31;
    if (n >= NN) return;
    float acc = bf2f(h[(size_t)n * HD + c]);  // self-loop (pre-scaled by dis[n])
    int e = row_ptr[n], end = row_ptr[n + 1];
    // peel to 16B alignment of csr_src
    while (e < end && (e & 3)) {
        acc += bf2f(h[(size_t)csr_src[e] * HD + c]);
        ++e;
    }
    for (; e + 7 < end; e += 8) {
        int4 a = *reinterpret_cast<const int4*>(csr_src + e);
        int4 b = *reinterpret_cast<const int4*>(csr_src + e + 4);
        float v0 = bf2f(h[(size_t)a.x * HD + c]);
        float v1 = bf2f(h[(size_t)a.y * HD + c]);
        float v2 = bf2f(h[(size_t)a.z * HD + c]);
        float v3 = bf2f(h[(size_t)a.w * HD + c]);
        float v4 = bf2f(h[(size_t)b.x * HD + c]);
        float v5 = bf2f(h[(size_t)b.y * HD + c]);
        float v6 = bf2f(h[(size_t)b.z * HD + c]);
        float v7 = bf2f(h[(size_t)b.w * HD + c]);
        acc += ((v0 + v1) + (v2 + v3)) + ((v4 + v5) + (v6 + v7));
    }
    if (e + 3 < end) {
        int4 a = *reinterpret_cast<const int4*>(csr_src + e);
        float v0 = bf2f(h[(size_t)a.x * HD + c]);
        float v1 = bf2f(h[(size_t)a.y * HD + c]);
        float v2 = bf2f(h[(size_t)a.z * HD + c]);
        float v3 = bf2f(h[(size_t)a.w * HD + c]);
        acc += (v0 + v1) + (v2 + v3);
        e += 4;
    }
    for (; e < end; ++e)
        acc += bf2f(h[(size_t)csr_src[e] * HD + c]);

    float v = fmaxf(acc * dis[n] + bias[c], 0.f);
    if (DO_LN) {
        float s = v, s2 = v * v;
#pragma unroll
        for (int m = 16; m >= 1; m >>= 1) {
            s += __shfl_xor(s, m, 32);
            s2 += __shfl_xor(s2, m, 32);
        }
        float mean = s * (1.f / 32.f);
        float var = s2 * (1.f / 32.f) - mean * mean;
        v = (v - mean) * rsqrtf(var + LN_EPS) * g[c] + bln[c];
    }
    out[(size_t)n * HD + c] = v;
}

// ---------------- final: MLP head + log_softmax ----------------

__global__ void k_final(const float* __restrict__ hin,
                        const float* __restrict__ w1, const float* __restrict__ mb1,
                        const float* __restrict__ w2, const float* __restrict__ mb2,
                        float* __restrict__ out) {
    __shared__ float sw1[HD * MID], sw2[MID * OUTD], sb1[MID], sb2[OUTD];
    for (int t = threadIdx.x; t < HD * MID; t += blockDim.x) sw1[t] = w1[t];
    for (int t = threadIdx.x; t < MID * OUTD; t += blockDim.x) sw2[t] = w2[t];
    if (threadIdx.x < MID) sb1[threadIdx.x] = mb1[threadIdx.x];
    if (threadIdx.x < OUTD) sb2[threadIdx.x] = mb2[threadIdx.x];
    __syncthreads();
    int n = blockIdx.x * blockDim.x + threadIdx.x;
    if (n >= NN) return;
    float h[HD];
    const float* ar = hin + (size_t)n * HD;
#pragma unroll
    for (int k = 0; k < HD; ++k) h[k] = ar[k];
    float t[MID];
#pragma unroll
    for (int j = 0; j < MID; ++j) {
        float a = sb1[j];
#pragma unroll
        for (int k = 0; k < HD; ++k) a += h[k] * sw1[k * MID + j];
        t[j] = fmaxf(a, 0.f);
    }
    float o[OUTD];
#pragma unroll
    for (int j = 0; j < OUTD; ++j) {
        float a = sb2[j];
#pragma unroll
        for (int k = 0; k < MID; ++k) a += t[k] * sw2[k * OUTD + j];
        o[j] = a;
    }
    float mx = o[0];
#pragma unroll
    for (int j = 1; j < OUTD; ++j) mx = fmaxf(mx, o[j]);
    float se = 0.f;
#pragma unroll
    for (int j = 0; j < OUTD; ++j) se += __expf(o[j] - mx);
    float lse = __logf(se) + mx;
    float* orow = out + (size_t)n * OUTD;
#pragma unroll
    for (int j = 0; j < OUTD; ++j) orow[j] = o[j] - lse;
}

// ---------------- launch ----------------

extern "C" void kernel_launch(void* const* d_in, const int* in_sizes, int n_in,
                              void* d_out, int out_size, void* d_ws, size_t ws_size,
                              hipStream_t stream) {
    const float* x     = (const float*)d_in[0];
    const int*   ei    = (const int*)d_in[1];
    const float* W0    = (const float*)d_in[2];
    const float* b0    = (const float*)d_in[3];
    const float* W1    = (const float*)d_in[4];
    const float* b1    = (const float*)d_in[5];
    const float* W2    = (const float*)d_in[6];
    const float* b2    = (const float*)d_in[7];
    const float* ln0_g = (const float*)d_in[8];
    const float* ln0_b = (const float*)d_in[9];
    const float* ln1_g = (const float*)d_in[10];
    const float* ln1_b = (const float*)d_in[11];
    const float* mp_w1 = (const float*)d_in[12];
    const float* mp_b1 = (const float*)d_in[13];
    const float* mp_w2 = (const float*)d_in[14];
    const float* mp_b2 = (const float*)d_in[15];
    float* out = (float*)d_out;

    const int* src = ei;        // edge_index[0]
    const int* dst = ei + NE;   // edge_index[1]

    char* w = (char*)d_ws;
    auto align256 = [](size_t v) { return (v + 255) & ~(size_t)255; };
    int* g_bincur  = (int*)w;   w += align256((size_t)NB * 4);
    int* g_binexcl = (int*)w;   w += align256((size_t)NB * 4);
    int* row_ptr   = (int*)w;   w += align256((size_t)(NN + 1) * 4);
    float* dis     = (float*)w; w += align256((size_t)NN * 4);
    char* uni = w;              // union region (staging vs activations)
    unsigned int* staged = (unsigned int*)uni;                    // NB*CAP*4 = 16.0 MB
    unsigned short* bufB = (unsigned short*)uni;                  // bf16 hs, 6.4 MB
    float* bufA = (float*)(uni + align256((size_t)NN * HD * 2));  // f32 acts, 12.8 MB
    size_t uni_sz = align256((size_t)NB * CAP * 4);
    size_t uni_sz2 = align256((size_t)NN * HD * 2) + align256((size_t)NN * HD * 4);
    w = uni + (uni_sz > uni_sz2 ? uni_sz : uni_sz2);
    int* csr_src = (int*)w;

    const int BS = 256;
    int gN   = (NN + BS - 1) / BS;          // 391
    int gA   = (NE + EPB - 1) / EPB;        // 391
    int gN32 = (NN * HD + BS - 1) / BS;

    // CSR build (binned counting sort)
    k_zero_bins<<<1, 512, 0, stream>>>(g_bincur);
    k_binA<<<gA, BS, 0, stream>>>(src, dst, g_bincur, staged);
    k_binscan<<<1, 512, 0, stream>>>(g_bincur, g_binexcl, row_ptr);
    k_binC<<<NB, BS, 0, stream>>>(g_bincur, g_binexcl, staged, row_ptr, dis, csr_src);

    // layer 0
    k_gemm<DIN><<<gN, BS, 0, stream>>>(x, W0, dis, bufB);
    k_gather<1><<<gN32, BS, 0, stream>>>(row_ptr, csr_src, dis, bufB, b0,
                                         ln0_g, ln0_b, bufA);
    // layer 1
    k_gemm<HD><<<gN, BS, 0, stream>>>(bufA, W1, dis, bufB);
    k_gather<1><<<gN32, BS, 0, stream>>>(row_ptr, csr_src, dis, bufB, b1,
                                         ln1_g, ln1_b, bufA);
    // layer 2 (no LN)
    k_gemm<HD><<<gN, BS, 0, stream>>>(bufA, W2, dis, bufB);
    k_gather<0><<<gN32, BS, 0, stream>>>(row_ptr, csr_src, dis, bufB, b2,
                                         nullptr, nullptr, bufA);

    // head
    k_final<<<gN, BS, 0, stream>>>(bufA, mp_w1, mp_b1, mp_w2, mp_b2, out);
}